// Round 1
// baseline (154.830 us; speedup 1.0000x reference)
//
#include <hip/hip_runtime.h>
#include <hip/hip_bf16.h>

// Problem constants: B=32, C=128, L=256, K=2 (Chebyshev order)
// Simplification: deg==1 -> D=I -> L_t = -adj.
// out = relu( x @ Theta0 + rhs1 @ Theta1 ), rhs1[b] = -(adjT[b] @ x[b])
// adjT[b][j][i] = tmpS[b,i,j]/colsum_j,  tmpS = exp(relu((1-diffn)*a))

#define NB 32
#define NC 128
#define NL 256

// ---------------- Kernel 1: pairwise L1 distance ----------------
// diff[b][i][j] = sum_l |x[b,i,l] - x[b,j,l]|   (symmetric in i,j)
// grid: 256 blocks (b in [0,32), itile in [0,8)), 256 threads
__global__ __launch_bounds__(256) void k_pairdist(const float* __restrict__ x,
                                                  float* __restrict__ diff) {
    int bid = blockIdx.x;
    int b  = bid >> 3;
    int i0 = (bid & 7) * 16;
    __shared__ float xi[16 * 260];   // padded stride 260 (float4-aligned, 2-way banks)
    __shared__ float xj[16 * 260];
    int tid = threadIdx.x;
    const float4* x4 = (const float4*)(x + (size_t)b * NC * NL);

    // load 16 rows of x for the i-tile (coalesced float4)
    for (int idx = tid; idx < 16 * 64; idx += 256) {
        int r = idx >> 6, c = idx & 63;
        *(float4*)&xi[r * 260 + c * 4] = x4[(i0 + r) * 64 + c];
    }

    int il = tid >> 4;   // 0..15
    int jl = tid & 15;   // 0..15

    for (int jt = 0; jt < 8; ++jt) {
        for (int idx = tid; idx < 16 * 64; idx += 256) {
            int r = idx >> 6, c = idx & 63;
            *(float4*)&xj[r * 260 + c * 4] = x4[(jt * 16 + r) * 64 + c];
        }
        __syncthreads();
        float acc = 0.f;
        #pragma unroll 8
        for (int l4 = 0; l4 < 64; ++l4) {
            float4 u = *(const float4*)&xi[il * 260 + l4 * 4];
            float4 v = *(const float4*)&xj[jl * 260 + l4 * 4];
            acc += fabsf(u.x - v.x) + fabsf(u.y - v.y) +
                   fabsf(u.z - v.z) + fabsf(u.w - v.w);
        }
        diff[(size_t)b * NC * NC + (i0 + il) * NC + jt * 16 + jl] = acc;
        __syncthreads();
    }
}

// ---------------- Kernel 2: batch L2 norm (reciprocal) + transpose a ----------------
// rnorm[i][j] = 1/max(sqrt(sum_b diff^2), 1e-12);  aT[j][i] = a[i][j]
__global__ __launch_bounds__(256) void k_norm_at(const float* __restrict__ diff,
                                                 const float* __restrict__ a,
                                                 float* __restrict__ rnorm,
                                                 float* __restrict__ aT) {
    int idx = blockIdx.x * 256 + threadIdx.x;  // 0..16383 -> (i,j)
    float s = 0.f;
    #pragma unroll
    for (int b = 0; b < NB; ++b) {
        float v = diff[(size_t)b * NC * NC + idx];
        s = fmaf(v, v, s);
    }
    rnorm[idx] = 1.0f / fmaxf(sqrtf(s), 1e-12f);
    int i = idx >> 7, j = idx & 127;
    aT[j * NC + i] = a[idx];
}

// ---------------- Kernel 3: normalized adjacency (transposed) ----------------
// block = (b, j); thread i: s_i = exp(relu((1 - diff*rnorm)*a[i][j])); adjT[b][j][i] = s_i/sum_i s_i
__global__ __launch_bounds__(128) void k_adjt(const float* __restrict__ diff,
                                              const float* __restrict__ rnorm,
                                              const float* __restrict__ aT,
                                              float* __restrict__ adjT) {
    int bid = blockIdx.x;          // b*128 + j
    int b = bid >> 7, j = bid & 127;
    int i = threadIdx.x;
    // use symmetry: diff[b,i,j] == diff[b,j,i]; rnorm symmetric too -> coalesced in i
    float d  = diff[(size_t)b * NC * NC + j * NC + i];
    float rn = rnorm[j * NC + i];
    float av = aT[j * NC + i];
    float s = expf(fmaxf((1.0f - d * rn) * av, 0.0f));
    // reduce over 128 threads (2 waves)
    float t = s;
    #pragma unroll
    for (int off = 32; off; off >>= 1) t += __shfl_xor(t, off);
    __shared__ float partial[2];
    if ((threadIdx.x & 63) == 0) partial[threadIdx.x >> 6] = t;
    __syncthreads();
    float total = partial[0] + partial[1];
    adjT[(size_t)b * NC * NC + j * NC + i] = s / total;
}

// ---------------- Kernel 4a: rhs1[b] = -(adjT[b] @ x[b])  [128x128]@[128x256] ----------------
// 64x64 tile, BK=32, 256 threads, 4x4 per thread
__global__ __launch_bounds__(256) void k_gemm_rhs(const float* __restrict__ adjT,
                                                  const float* __restrict__ x,
                                                  float* __restrict__ rhs1) {
    int bid = blockIdx.x;
    int b = bid >> 3;
    int t = bid & 7;
    int m0 = (t >> 2) * 64;   // 2 m-tiles
    int n0 = (t & 3) * 64;    // 4 n-tiles
    const float* A  = adjT + (size_t)b * NC * NC;   // [128][128]
    const float* Bm = x    + (size_t)b * NC * NL;   // [128][256]
    __shared__ float As[32 * 68];   // [k][m], padded
    __shared__ float Bs[32 * 68];   // [k][n], padded
    int tid = threadIdx.x;
    int tx = tid & 15, ty = tid >> 4;
    float acc[4][4] = {};
    for (int k0 = 0; k0 < NC; k0 += 32) {
        for (int idx = tid; idx < 64 * 32; idx += 256) {
            int m = idx >> 5, k = idx & 31;
            As[k * 68 + m] = A[(m0 + m) * NC + k0 + k];
        }
        for (int idx = tid; idx < 32 * 64; idx += 256) {
            int k = idx >> 6, n = idx & 63;
            Bs[k * 68 + n] = Bm[(k0 + k) * NL + n0 + n];
        }
        __syncthreads();
        #pragma unroll
        for (int kk = 0; kk < 32; ++kk) {
            float4 av = *(const float4*)&As[kk * 68 + ty * 4];
            float4 bv = *(const float4*)&Bs[kk * 68 + tx * 4];
            float ar[4] = {av.x, av.y, av.z, av.w};
            float br[4] = {bv.x, bv.y, bv.z, bv.w};
            #pragma unroll
            for (int i = 0; i < 4; ++i)
                #pragma unroll
                for (int jj = 0; jj < 4; ++jj)
                    acc[i][jj] = fmaf(ar[i], br[jj], acc[i][jj]);
        }
        __syncthreads();
    }
    #pragma unroll
    for (int i = 0; i < 4; ++i)
        #pragma unroll
        for (int jj = 0; jj < 4; ++jj)
            rhs1[(size_t)b * NC * NL + (m0 + ty * 4 + i) * NL + n0 + tx * 4 + jj] = -acc[i][jj];
}

// ---------------- Kernel 4b: out = relu( concat(x, rhs1) @ Theta[512x256] ) ----------------
__global__ __launch_bounds__(256) void k_gemm_out(const float* __restrict__ x,
                                                  const float* __restrict__ rhs1,
                                                  const float* __restrict__ Theta,
                                                  float* __restrict__ out) {
    int bid = blockIdx.x;
    int b = bid >> 3;
    int t = bid & 7;
    int m0 = (t >> 2) * 64;
    int n0 = (t & 3) * 64;
    __shared__ float As[32 * 68];
    __shared__ float Bs[32 * 68];
    int tid = threadIdx.x;
    int tx = tid & 15, ty = tid >> 4;
    float acc[4][4] = {};
    for (int k0 = 0; k0 < 512; k0 += 32) {
        const float* Ab = (k0 < 256) ? (x + (size_t)b * NC * NL + k0)
                                     : (rhs1 + (size_t)b * NC * NL + (k0 - 256));
        for (int idx = tid; idx < 64 * 32; idx += 256) {
            int m = idx >> 5, k = idx & 31;
            As[k * 68 + m] = Ab[(m0 + m) * NL + k];
        }
        for (int idx = tid; idx < 32 * 64; idx += 256) {
            int k = idx >> 6, n = idx & 63;
            Bs[k * 68 + n] = Theta[(k0 + k) * NL + n0 + n];
        }
        __syncthreads();
        #pragma unroll
        for (int kk = 0; kk < 32; ++kk) {
            float4 av = *(const float4*)&As[kk * 68 + ty * 4];
            float4 bv = *(const float4*)&Bs[kk * 68 + tx * 4];
            float ar[4] = {av.x, av.y, av.z, av.w};
            float br[4] = {bv.x, bv.y, bv.z, bv.w};
            #pragma unroll
            for (int i = 0; i < 4; ++i)
                #pragma unroll
                for (int jj = 0; jj < 4; ++jj)
                    acc[i][jj] = fmaf(ar[i], br[jj], acc[i][jj]);
        }
        __syncthreads();
    }
    #pragma unroll
    for (int i = 0; i < 4; ++i)
        #pragma unroll
        for (int jj = 0; jj < 4; ++jj)
            out[(size_t)b * NC * NL + (m0 + ty * 4 + i) * NL + n0 + tx * 4 + jj] =
                fmaxf(acc[i][jj], 0.0f);
}

extern "C" void kernel_launch(void* const* d_in, const int* in_sizes, int n_in,
                              void* d_out, int out_size, void* d_ws, size_t ws_size,
                              hipStream_t stream) {
    const float* x     = (const float*)d_in[0];   // [32,128,256]
    const float* a     = (const float*)d_in[1];   // [128,128]
    const float* Theta = (const float*)d_in[2];   // [2,256,256] == [512,256]
    float* out = (float*)d_out;
    float* ws  = (float*)d_ws;

    float* diff  = ws;                   // 524288 floats (2 MB)
    float* rnorm = diff + 524288;        // 16384
    float* aT    = rnorm + 16384;        // 16384
    float* adjT  = aT + 16384;           // 524288
    float* rhs1  = adjT + 524288;        // 1048576  (total ~8.5 MB)

    k_pairdist<<<dim3(256), dim3(256), 0, stream>>>(x, diff);
    k_norm_at<<<dim3(64), dim3(256), 0, stream>>>(diff, a, rnorm, aT);
    k_adjt<<<dim3(NB * NC), dim3(128), 0, stream>>>(diff, rnorm, aT, adjT);
    k_gemm_rhs<<<dim3(256), dim3(256), 0, stream>>>(adjT, x, rhs1);
    k_gemm_out<<<dim3(256), dim3(256), 0, stream>>>(x, rhs1, Theta, out);
}

// Round 2
// 100.320 us; speedup vs baseline: 1.5434x; 1.5434x over previous
//
#include <hip/hip_runtime.h>
#include <hip/hip_bf16.h>

// B=32, C=128, L=256, K=2. deg==1 -> L_t = -adj.
// out = relu( x@Th0 - adjT@(x@Th1) )
//   xTh  = x_flat[4096,256] @ ThT'   (flat bf16 MFMA GEMM, N=512)
//   out  = relu(xTh0 - adjT[b]@xTh1[b])  (batched bf16 MFMA, fused epilogue)

#define NB 32
#define NC 128
#define NL 256

typedef short bf16x8 __attribute__((ext_vector_type(8)));
typedef float f32x4 __attribute__((ext_vector_type(4)));

static __device__ __forceinline__ unsigned short f2bf(float f) {
    unsigned u = __builtin_bit_cast(unsigned, f);
    u += 0x7fff + ((u >> 16) & 1);            // round-to-nearest-even
    return (unsigned short)(u >> 16);
}

// ---------------- Kernel 0: convert x->bf16 (vec4) and Theta -> transposed bf16 ----------------
// thT[t*256+n][l] = Theta[t][l][n]
__global__ __launch_bounds__(256) void k_cvt(const float* __restrict__ x,
                                             const float* __restrict__ Theta,
                                             unsigned short* __restrict__ xb,
                                             unsigned short* __restrict__ thT) {
    int idx = blockIdx.x * 256 + threadIdx.x;
    if (idx < 262144) {
        float4 v = ((const float4*)x)[idx];
        ushort4 o;
        o.x = f2bf(v.x); o.y = f2bf(v.y); o.z = f2bf(v.z); o.w = f2bf(v.w);
        ((ushort4*)xb)[idx] = o;
    } else {
        int e = idx - 262144;                 // 0..131071
        int t = e >> 16, n = (e >> 8) & 255, l = e & 255;
        thT[e] = f2bf(Theta[t * 65536 + l * 256 + n]);
    }
}

// ---------------- Kernel 1: pairwise L1 distance, i<=j tiles only ----------------
__device__ const unsigned char TI36[36] = {0,0,0,0,0,0,0,0, 1,1,1,1,1,1,1, 2,2,2,2,2,2,
                                           3,3,3,3,3, 4,4,4,4, 5,5,5, 6,6, 7};
__device__ const unsigned char TJ36[36] = {0,1,2,3,4,5,6,7, 1,2,3,4,5,6,7, 2,3,4,5,6,7,
                                           3,4,5,6,7, 4,5,6,7, 5,6,7, 6,7, 7};

__global__ __launch_bounds__(256) void k_pairdist(const float* __restrict__ x,
                                                  float* __restrict__ diff) {
    int bid = blockIdx.x;
    int b = bid / 36, p = bid - b * 36;
    int i0 = TI36[p] * 16, j0 = TJ36[p] * 16;
    __shared__ float xi[16 * 260];
    __shared__ float xj[16 * 260];
    __shared__ float sT[16 * 17];
    const float4* x4 = (const float4*)(x + (size_t)b * NC * NL);
    int tid = threadIdx.x;
    for (int idx = tid; idx < 16 * 64; idx += 256) {
        int r = idx >> 6, c = idx & 63;
        *(float4*)&xi[r * 260 + c * 4] = x4[(i0 + r) * 64 + c];
        *(float4*)&xj[r * 260 + c * 4] = x4[(j0 + r) * 64 + c];
    }
    __syncthreads();
    int il = tid >> 4, jl = tid & 15;
    float acc = 0.f;
    #pragma unroll 8
    for (int l4 = 0; l4 < 64; ++l4) {
        float4 u = *(const float4*)&xi[il * 260 + l4 * 4];
        float4 v = *(const float4*)&xj[jl * 260 + l4 * 4];
        acc += fabsf(u.x - v.x) + fabsf(u.y - v.y) +
               fabsf(u.z - v.z) + fabsf(u.w - v.w);
    }
    float* D = diff + (size_t)b * NC * NC;
    D[(i0 + il) * NC + j0 + jl] = acc;        // direct, coalesced
    sT[jl * 17 + il] = acc;
    __syncthreads();
    D[(j0 + il) * NC + i0 + jl] = sT[il * 17 + jl];  // mirror, coalesced via LDS transpose
}

// ---------------- Kernel 2: batch L2 norm (reciprocal) + transpose a ----------------
__global__ __launch_bounds__(256) void k_norm_at(const float* __restrict__ diff,
                                                 const float* __restrict__ a,
                                                 float* __restrict__ rnorm,
                                                 float* __restrict__ aT) {
    int idx = blockIdx.x * 256 + threadIdx.x;  // (i,j)
    float s = 0.f;
    #pragma unroll
    for (int b = 0; b < NB; ++b) {
        float v = diff[(size_t)b * NC * NC + idx];
        s = fmaf(v, v, s);
    }
    rnorm[idx] = 1.0f / fmaxf(sqrtf(s), 1e-12f);
    int i = idx >> 7, j = idx & 127;
    aT[j * NC + i] = a[idx];
}

// ---------------- Kernel 3: normalized adjacency (transposed), bf16 out ----------------
__global__ __launch_bounds__(128) void k_adjt(const float* __restrict__ diff,
                                              const float* __restrict__ rnorm,
                                              const float* __restrict__ aT,
                                              unsigned short* __restrict__ adjTb) {
    int bid = blockIdx.x;          // b*128 + j
    int b = bid >> 7, j = bid & 127;
    int i = threadIdx.x;
    float d  = diff[(size_t)b * NC * NC + j * NC + i];   // symmetric read
    float rn = rnorm[j * NC + i];
    float av = aT[j * NC + i];
    float s = expf(fmaxf((1.0f - d * rn) * av, 0.0f));
    float t = s;
    #pragma unroll
    for (int off = 32; off; off >>= 1) t += __shfl_xor(t, off);
    __shared__ float partial[2];
    if ((threadIdx.x & 63) == 0) partial[threadIdx.x >> 6] = t;
    __syncthreads();
    float total = partial[0] + partial[1];
    adjTb[(size_t)b * NC * NC + j * NC + i] = f2bf(s / total);
}

// ---------------- Kernel 4: xTh = x_flat[4096,256] @ ThT  (MFMA, no LDS) ----------------
// blocks: 1024 = 64 mtiles x 16 ntiles(32 wide). 4 waves, each 16x32.
// t<8 (n<256): write xTh0 f32 [b][i][n].  t>=8: write xTh1T bf16 [b][n][i].
__global__ __launch_bounds__(256) void k_gemm_xth(const unsigned short* __restrict__ xb,
                                                  const unsigned short* __restrict__ thT,
                                                  float* __restrict__ xTh0,
                                                  unsigned short* __restrict__ xTh1T) {
    int bid = blockIdx.x;
    int mt = bid >> 4, nt = bid & 15;
    int m0 = mt * 64, n0 = nt * 32;
    int tid = threadIdx.x, w = tid >> 6, lane = tid & 63;
    int lr = lane & 15, lg = lane >> 4;
    const unsigned short* Ap  = xb  + (size_t)(m0 + w * 16 + lr) * 256 + lg * 8;
    const unsigned short* Bp0 = thT + (size_t)(n0 + lr) * 256 + lg * 8;
    const unsigned short* Bp1 = Bp0 + 16 * 256;
    f32x4 acc0 = {0.f, 0.f, 0.f, 0.f}, acc1 = {0.f, 0.f, 0.f, 0.f};
    #pragma unroll
    for (int ks = 0; ks < 8; ++ks) {
        bf16x8 av = *(const bf16x8*)(Ap + ks * 32);
        bf16x8 b0 = *(const bf16x8*)(Bp0 + ks * 32);
        bf16x8 b1 = *(const bf16x8*)(Bp1 + ks * 32);
        acc0 = __builtin_amdgcn_mfma_f32_16x16x32_bf16(av, b0, acc0, 0, 0, 0);
        acc1 = __builtin_amdgcn_mfma_f32_16x16x32_bf16(av, b1, acc1, 0, 0, 0);
    }
    int orow = m0 + w * 16 + lg * 4;          // output rows orow..orow+3 (same batch)
    int bt = orow >> 7, ir = orow & 127;
    if (n0 < 256) {
        float* O = xTh0 + (size_t)bt * 32768 + (size_t)ir * 256 + n0 + lr;
        #pragma unroll
        for (int r = 0; r < 4; ++r) {
            O[r * 256]      = acc0[r];
            O[r * 256 + 16] = acc1[r];
        }
    } else {
        int n1 = n0 - 256;
        unsigned short* O = xTh1T + (size_t)bt * 32768 + (size_t)(n1 + lr) * 128 + ir;
        ushort4 p0, p1;
        p0.x = f2bf(acc0[0]); p0.y = f2bf(acc0[1]); p0.z = f2bf(acc0[2]); p0.w = f2bf(acc0[3]);
        p1.x = f2bf(acc1[0]); p1.y = f2bf(acc1[1]); p1.z = f2bf(acc1[2]); p1.w = f2bf(acc1[3]);
        *(ushort4*)O = p0;
        *(ushort4*)(O + 16 * 128) = p1;
    }
}

// ---------------- Kernel 5: out = relu(xTh0 - adjT@xTh1)  (batched MFMA, fused) ----------------
// 512 blocks: b*16 + (mt2:1bit, nt8:3bits). 4 waves, each 16x32. K=128.
__global__ __launch_bounds__(256) void k_gemm_e(const unsigned short* __restrict__ adjTb,
                                                const unsigned short* __restrict__ xTh1T,
                                                const float* __restrict__ xTh0,
                                                float* __restrict__ out) {
    int bid = blockIdx.x;
    int b = bid >> 4, t16 = bid & 15;
    int j0 = (t16 >> 3) * 64, n0 = (t16 & 7) * 32;
    int tid = threadIdx.x, w = tid >> 6, lane = tid & 63;
    int lr = lane & 15, lg = lane >> 4;
    const unsigned short* Ap  = adjTb + (size_t)b * 16384 + (size_t)(j0 + w * 16 + lr) * 128 + lg * 8;
    const unsigned short* Bp0 = xTh1T + (size_t)b * 32768 + (size_t)(n0 + lr) * 128 + lg * 8;
    const unsigned short* Bp1 = Bp0 + 16 * 128;
    f32x4 acc0 = {0.f, 0.f, 0.f, 0.f}, acc1 = {0.f, 0.f, 0.f, 0.f};
    #pragma unroll
    for (int ks = 0; ks < 4; ++ks) {
        bf16x8 av = *(const bf16x8*)(Ap + ks * 32);
        bf16x8 b0 = *(const bf16x8*)(Bp0 + ks * 32);
        bf16x8 b1 = *(const bf16x8*)(Bp1 + ks * 32);
        acc0 = __builtin_amdgcn_mfma_f32_16x16x32_bf16(av, b0, acc0, 0, 0, 0);
        acc1 = __builtin_amdgcn_mfma_f32_16x16x32_bf16(av, b1, acc1, 0, 0, 0);
    }
    int j = j0 + w * 16 + lg * 4;
    const float* X0 = xTh0 + (size_t)b * 32768 + (size_t)j * 256 + n0 + lr;
    float* O = out + (size_t)b * 32768 + (size_t)j * 256 + n0 + lr;
    #pragma unroll
    for (int r = 0; r < 4; ++r) {
        O[r * 256]      = fmaxf(X0[r * 256]      - acc0[r], 0.f);
        O[r * 256 + 16] = fmaxf(X0[r * 256 + 16] - acc1[r], 0.f);
    }
}

extern "C" void kernel_launch(void* const* d_in, const int* in_sizes, int n_in,
                              void* d_out, int out_size, void* d_ws, size_t ws_size,
                              hipStream_t stream) {
    const float* x     = (const float*)d_in[0];   // [32,128,256]
    const float* a     = (const float*)d_in[1];   // [128,128]
    const float* Theta = (const float*)d_in[2];   // [2,256,256]
    float* out = (float*)d_out;
    float* f0  = (float*)d_ws;

    // workspace (f32 units); diff is dead after k_adjt, so xTh1T aliases it.
    float*          diff  = f0;                               // 524288
    unsigned short* xTh1T = (unsigned short*)f0;              // 1048576 bf16 (alias)
    float*          rnorm = f0 + 524288;                      // 16384
    float*          aT    = f0 + 540672;                      // 16384
    float*          xTh0  = f0 + 557056;                      // 1048576
    unsigned short* xb    = (unsigned short*)(f0 + 1605632);  // 1048576 bf16
    unsigned short* thT   = (unsigned short*)(f0 + 2129920);  // 131072 bf16
    unsigned short* adjTb = (unsigned short*)(f0 + 2195456);  // 524288 bf16
    // total 2457600 f32 = 9.83 MB

    k_cvt     <<<dim3(1536), dim3(256), 0, stream>>>(x, Theta, xb, thT);
    k_pairdist<<<dim3(NB * 36), dim3(256), 0, stream>>>(x, diff);
    k_norm_at <<<dim3(64), dim3(256), 0, stream>>>(diff, a, rnorm, aT);
    k_adjt    <<<dim3(NB * NC), dim3(128), 0, stream>>>(diff, rnorm, aT, adjTb);
    k_gemm_xth<<<dim3(1024), dim3(256), 0, stream>>>(xb, thT, xTh0, xTh1T);
    k_gemm_e  <<<dim3(512), dim3(256), 0, stream>>>(adjTb, xTh1T, xTh0, out);
}

// Round 4
// 92.297 us; speedup vs baseline: 1.6775x; 1.0869x over previous
//
#include <hip/hip_runtime.h>
#include <hip/hip_bf16.h>

// B=32, C=128, L=256, K=2. deg==1 -> L_t = -adj.
// out = relu( x@Th0 - adjT@(x@Th1) )
// 4 kernels: k_pre (pairdist + cvt/transposes), k_adj (norm+adjacency),
//            k_xth (flat [4096,256]@[256,512] bf16 MFMA), k_out (batched MFMA + epilogue)

#define NB 32
#define NC 128
#define NL 256

typedef short bf16x8 __attribute__((ext_vector_type(8)));
typedef float f32x4 __attribute__((ext_vector_type(4)));

static __device__ __forceinline__ unsigned short f2bf(float f) {
    unsigned u = __builtin_bit_cast(unsigned, f);
    u += 0x7fff + ((u >> 16) & 1);            // RNE
    return (unsigned short)(u >> 16);
}

__device__ const unsigned char TI36[36] = {0,0,0,0,0,0,0,0, 1,1,1,1,1,1,1, 2,2,2,2,2,2,
                                           3,3,3,3,3, 4,4,4,4, 5,5,5, 6,6, 7};
__device__ const unsigned char TJ36[36] = {0,1,2,3,4,5,6,7, 1,2,3,4,5,6,7, 2,3,4,5,6,7,
                                           3,4,5,6,7, 4,5,6,7, 5,6,7, 6,7, 7};

// ---------------- K1: pairdist (i<=j) + x->bf16 + Theta^T bf16 + a^T ----------------
// blocks [0,1152): pairdist; [1152,2176): xb cvt; [2176,2208): thT; [2208,2212): aT
__global__ __launch_bounds__(256) void k_pre(const float* __restrict__ x,
                                             const float* __restrict__ Theta,
                                             const float* __restrict__ a,
                                             float* __restrict__ diff,
                                             unsigned short* __restrict__ xb,
                                             unsigned short* __restrict__ thT,
                                             float* __restrict__ aT) {
    __shared__ float smem[8592];   // pairdist: xi 4160 | xj 4160 | sT 272 ; transposes: [64][65]
    int bid = blockIdx.x;
    int tid = threadIdx.x;

    if (bid < 1152) {
        int b = bid / 36, p = bid - b * 36;
        int i0 = TI36[p] * 16, j0 = TJ36[p] * 16;
        float* xi = smem;
        float* xj = smem + 4160;
        float* sT = smem + 8320;
        const float4* x4 = (const float4*)(x + (size_t)b * NC * NL);
        for (int idx = tid; idx < 16 * 64; idx += 256) {
            int r = idx >> 6, c = idx & 63;
            *(float4*)&xi[r * 260 + c * 4] = x4[(i0 + r) * 64 + c];
            *(float4*)&xj[r * 260 + c * 4] = x4[(j0 + r) * 64 + c];
        }
        __syncthreads();
        int il = tid >> 4, jl = tid & 15;
        float acc = 0.f;
        #pragma unroll 8
        for (int l4 = 0; l4 < 64; ++l4) {
            float4 u = *(const float4*)&xi[il * 260 + l4 * 4];
            float4 v = *(const float4*)&xj[jl * 260 + l4 * 4];
            acc += fabsf(u.x - v.x) + fabsf(u.y - v.y) +
                   fabsf(u.z - v.z) + fabsf(u.w - v.w);
        }
        float* D = diff + (size_t)b * NC * NC;
        D[(i0 + il) * NC + j0 + jl] = acc;
        sT[jl * 17 + il] = acc;
        __syncthreads();
        D[(j0 + il) * NC + i0 + jl] = sT[il * 17 + jl];
    } else if (bid < 2176) {
        int idx = (bid - 1152) * 256 + tid;       // 262144 float4 = all of x
        float4 v = ((const float4*)x)[idx];
        ushort4 o;
        o.x = f2bf(v.x); o.y = f2bf(v.y); o.z = f2bf(v.z); o.w = f2bf(v.w);
        ((ushort4*)xb)[idx] = o;
    } else if (bid < 2208) {
        // thT[t*256+n][l] = Theta[t][l][n]; 32 tiles of 64x64
        int tt = bid - 2176;
        int t = tt >> 4, rem = tt & 15;
        int l0 = (rem >> 2) * 64, n0 = (rem & 3) * 64;
        const float* Tp = Theta + (size_t)t * 65536;
        for (int it = tid; it < 4096; it += 256) {
            int r = it >> 6, c = it & 63;
            smem[r * 65 + c] = Tp[(l0 + r) * 256 + n0 + c];
        }
        __syncthreads();
        for (int it = tid; it < 4096; it += 256) {
            int r = it >> 6, c = it & 63;   // r = n-local, c = l-local
            thT[(size_t)(t * 256 + n0 + r) * 256 + l0 + c] = f2bf(smem[c * 65 + r]);
        }
    } else {
        // aT[j][i] = a[i][j]; 4 tiles of 64x64
        int tt = bid - 2208;
        int i0 = (tt >> 1) * 64, j0 = (tt & 1) * 64;
        for (int it = tid; it < 4096; it += 256) {
            int r = it >> 6, c = it & 63;
            smem[r * 65 + c] = a[(i0 + r) * NC + j0 + c];
        }
        __syncthreads();
        for (int it = tid; it < 4096; it += 256) {
            int r = it >> 6, c = it & 63;   // r = j-local, c = i-local
            aT[(j0 + r) * NC + i0 + c] = smem[c * 65 + r];
        }
    }
}

// ---------------- K2: fused batch-norm + adjacency (transposed, bf16) ----------------
// block = (b, j), 128 threads (i). Norms recomputed per block from L2-resident diff.
__global__ __launch_bounds__(128) void k_adj(const float* __restrict__ diff,
                                             const float* __restrict__ aT,
                                             unsigned short* __restrict__ adjTb) {
    int bid = blockIdx.x;
    int b = bid >> 7, j = bid & 127;
    int i = threadIdx.x;
    const float* Dj = diff + j * NC + i;      // diff[b'][j][i], symmetric
    float ss = 0.f;
    #pragma unroll
    for (int bb = 0; bb < NB; ++bb) {
        float v = Dj[(size_t)bb * NC * NC];
        ss = fmaf(v, v, ss);
    }
    float rn = 1.0f / fmaxf(sqrtf(ss), 1e-12f);
    float d  = Dj[(size_t)b * NC * NC];       // L1 hit
    float av = aT[j * NC + i];
    float s = __expf(fmaxf((1.0f - d * rn) * av, 0.0f));
    float t = s;
    #pragma unroll
    for (int off = 32; off; off >>= 1) t += __shfl_xor(t, off);
    __shared__ float partial[2];
    if ((i & 63) == 0) partial[i >> 6] = t;
    __syncthreads();
    float total = partial[0] + partial[1];
    adjTb[(size_t)b * NC * NC + j * NC + i] = f2bf(s / total);
}

// ---------------- K3: xTh = x_flat[4096,256] @ ThT  (MFMA, LDS-staged B) ----------------
// 512 blocks = 32 mtiles(128) x 16 ntiles(32). 4 waves, each 32m x 32n (2x2 frags).
// nt<8: write xTh0 f32 [b][i][n]; nt>=8: write xTh1T bf16 [b][n][i].
__global__ __launch_bounds__(256) void k_xth(const unsigned short* __restrict__ xb,
                                             const unsigned short* __restrict__ thT,
                                             float* __restrict__ xTh0,
                                             unsigned short* __restrict__ xTh1T) {
    __shared__ unsigned short Bs[8192];       // [32 n][256 k] bf16, XOR-swizzled, 16 KB
    int bid = blockIdx.x;
    int mt = bid >> 4, nt = bid & 15;
    int m0 = mt * 128, n0 = nt * 32;
    int tid = threadIdx.x, w = tid >> 6, lane = tid & 63;
    int lr = lane & 15, lg = lane >> 4;

    // stage B tile: 1024 x 16B chunks; swizzle byte ^= (n&7)<<4 on write AND read
    #pragma unroll
    for (int it = 0; it < 4; ++it) {
        int c = tid + it * 256;
        int n = c >> 5, kc = c & 31;
        bf16x8 v = *(const bf16x8*)(thT + (size_t)(n0 + n) * 256 + kc * 8);
        int dst = n * 512 + ((kc * 16) ^ ((n & 7) << 4));
        *(bf16x8*)((char*)Bs + dst) = v;
    }
    __syncthreads();

    const unsigned short* Ap0 = xb + (size_t)(m0 + w * 32 + lr) * 256 + lg * 8;
    const unsigned short* Ap1 = Ap0 + 16 * 256;
    f32x4 acc00 = {0.f,0.f,0.f,0.f}, acc01 = {0.f,0.f,0.f,0.f};
    f32x4 acc10 = {0.f,0.f,0.f,0.f}, acc11 = {0.f,0.f,0.f,0.f};
    int swz = (lr & 7) << 4;
    #pragma unroll
    for (int ks = 0; ks < 8; ++ks) {
        bf16x8 a0 = *(const bf16x8*)(Ap0 + ks * 32);
        bf16x8 a1 = *(const bf16x8*)(Ap1 + ks * 32);
        int kb = (ks * 64 + lg * 16) ^ swz;
        bf16x8 b0 = *(const bf16x8*)((char*)Bs + lr * 512 + kb);
        bf16x8 b1 = *(const bf16x8*)((char*)Bs + (16 + lr) * 512 + kb);
        acc00 = __builtin_amdgcn_mfma_f32_16x16x32_bf16(a0, b0, acc00, 0, 0, 0);
        acc01 = __builtin_amdgcn_mfma_f32_16x16x32_bf16(a0, b1, acc01, 0, 0, 0);
        acc10 = __builtin_amdgcn_mfma_f32_16x16x32_bf16(a1, b0, acc10, 0, 0, 0);
        acc11 = __builtin_amdgcn_mfma_f32_16x16x32_bf16(a1, b1, acc11, 0, 0, 0);
    }

    int ir0 = w * 32 + lg * 4;                // D: col=lr, row=lg*4+r (per frag)
    if (n0 < 256) {
        float* O = xTh0 + (size_t)mt * 32768 + (size_t)ir0 * 256 + n0 + lr;
        #pragma unroll
        for (int r = 0; r < 4; ++r) {
            O[r * 256]              = acc00[r];
            O[r * 256 + 16]         = acc01[r];
            O[(16 + r) * 256]       = acc10[r];
            O[(16 + r) * 256 + 16]  = acc11[r];
        }
    } else {
        int n1 = n0 - 256;
        unsigned short* O = xTh1T + (size_t)mt * 32768;
        ushort4 p;
        p.x = f2bf(acc00[0]); p.y = f2bf(acc00[1]); p.z = f2bf(acc00[2]); p.w = f2bf(acc00[3]);
        *(ushort4*)(O + (size_t)(n1 + lr) * 128 + ir0) = p;
        p.x = f2bf(acc01[0]); p.y = f2bf(acc01[1]); p.z = f2bf(acc01[2]); p.w = f2bf(acc01[3]);
        *(ushort4*)(O + (size_t)(n1 + 16 + lr) * 128 + ir0) = p;
        p.x = f2bf(acc10[0]); p.y = f2bf(acc10[1]); p.z = f2bf(acc10[2]); p.w = f2bf(acc10[3]);
        *(ushort4*)(O + (size_t)(n1 + lr) * 128 + ir0 + 16) = p;
        p.x = f2bf(acc11[0]); p.y = f2bf(acc11[1]); p.z = f2bf(acc11[2]); p.w = f2bf(acc11[3]);
        *(ushort4*)(O + (size_t)(n1 + 16 + lr) * 128 + ir0 + 16) = p;
    }
}

// ---------------- K4: out = relu(xTh0 - adjT@xTh1)  (batched MFMA, fused) ----------------
// 512 blocks: b*16 + (jt:1bit, nt:3bits). 4 waves, each 16j x 32n. K=128.
__global__ __launch_bounds__(256) void k_out(const unsigned short* __restrict__ adjTb,
                                             const unsigned short* __restrict__ xTh1T,
                                             const float* __restrict__ xTh0,
                                             float* __restrict__ out) {
    int bid = blockIdx.x;
    int b = bid >> 4, t16 = bid & 15;
    int j0 = (t16 >> 3) * 64, n0 = (t16 & 7) * 32;
    int tid = threadIdx.x, w = tid >> 6, lane = tid & 63;
    int lr = lane & 15, lg = lane >> 4;
    const unsigned short* Ap  = adjTb + (size_t)b * 16384 + (size_t)(j0 + w * 16 + lr) * 128 + lg * 8;
    const unsigned short* Bp0 = xTh1T + (size_t)b * 32768 + (size_t)(n0 + lr) * 128 + lg * 8;
    const unsigned short* Bp1 = Bp0 + 16 * 128;
    f32x4 acc0 = {0.f,0.f,0.f,0.f}, acc1 = {0.f,0.f,0.f,0.f};
    #pragma unroll
    for (int ks = 0; ks < 4; ++ks) {
        bf16x8 av = *(const bf16x8*)(Ap + ks * 32);
        bf16x8 b0 = *(const bf16x8*)(Bp0 + ks * 32);
        bf16x8 b1 = *(const bf16x8*)(Bp1 + ks * 32);
        acc0 = __builtin_amdgcn_mfma_f32_16x16x32_bf16(av, b0, acc0, 0, 0, 0);
        acc1 = __builtin_amdgcn_mfma_f32_16x16x32_bf16(av, b1, acc1, 0, 0, 0);
    }
    int j = j0 + w * 16 + lg * 4;
    const float* X0 = xTh0 + (size_t)b * 32768 + (size_t)j * 256 + n0 + lr;
    float* O = out + (size_t)b * 32768 + (size_t)j * 256 + n0 + lr;
    #pragma unroll
    for (int r = 0; r < 4; ++r) {
        O[r * 256]      = fmaxf(X0[r * 256]      - acc0[r], 0.f);
        O[r * 256 + 16] = fmaxf(X0[r * 256 + 16] - acc1[r], 0.f);
    }
}

extern "C" void kernel_launch(void* const* d_in, const int* in_sizes, int n_in,
                              void* d_out, int out_size, void* d_ws, size_t ws_size,
                              hipStream_t stream) {
    const float* x     = (const float*)d_in[0];   // [32,128,256]
    const float* a     = (const float*)d_in[1];   // [128,128]
    const float* Theta = (const float*)d_in[2];   // [2,256,256]
    float* out = (float*)d_out;
    float* f0  = (float*)d_ws;

    // workspace (f32 units); diff dead after k_adj -> xTh1T aliases it.
    float*          diff  = f0;                               // 524288 f32
    unsigned short* xTh1T = (unsigned short*)f0;              // 1048576 bf16 (alias)
    float*          aT    = f0 + 524288;                      // 16384 f32
    float*          xTh0  = f0 + 540672;                      // 1048576 f32
    unsigned short* xb    = (unsigned short*)(f0 + 1589248);  // 1048576 bf16
    unsigned short* thT   = (unsigned short*)(f0 + 2113536);  // 131072 bf16
    unsigned short* adjTb = (unsigned short*)(f0 + 2179072);  // 524288 bf16
    // total 2441216 f32 = 9.76 MB

    k_pre<<<dim3(2212), dim3(256), 0, stream>>>(x, Theta, a, diff, xb, thT, aT);
    k_adj<<<dim3(NB * NC), dim3(128), 0, stream>>>(diff, aT, adjTb);
    k_xth<<<dim3(512), dim3(256), 0, stream>>>(xb, thT, xTh0, xTh1T);
    k_out<<<dim3(512), dim3(256), 0, stream>>>(adjTb, xTh1T, xTh0, out);
}